// Round 7
// baseline (1804.528 us; speedup 1.0000x reference)
//
#include <hip/hip_runtime.h>

// RecyclingEmbedder: out[i][j][p] = b[p] + (bin(d_ij) fired ? W[p][bin] : 0)
// Output = 16-row table lookup -> pure write-BW problem (1.208 GB fp32).
//
// History:
//  R2(s1): nontemporal stores ~1.0 TB/s -> plain stores.
//  R1: 32 waves/CU: null. R3: flat fill-clone sweep: null (row-thrash DEAD).
//  R5: explicit 2-deep SW pipeline, columnar offsets: null (latency-chain DEAD).
//  R4 DIAG: t(n passes) = F + n*c fits F~150us fixed + c~256us/pass (4.7 TB/s);
//    single-pass stream stuck at ~400us (2.9-3.0 TB/s) across 5 structures.
//  Fill counters: FETCH~0 at 6.27 TB/s -> no blanket RFO policy on this chip.
//  R6: infra failure (Trio nursery exception), no signal. RESUBMITTED VERBATIM
//    (precedent: R2 infra failure -> identical R3 code ran fine).
//
// R7 = DECISIVE DIAGNOSTIC (retry): 4 sweeps in stream_kernel:
//   2x CONST-store sweep (fillBuffer clone in our kernel's context)
//   2x REAL table-lookup sweep (last pass writes the correct output)
// -> stream dispatch ~1.0-1.2ms = rank 1 in rocprof top-5 = first direct read
//    of FETCH_SIZE / WRITE_SIZE / hbm_gbps / occupancy for OUR store stream,
//    and const-vs-real rate separation via dur(R7)-dur(R4).
// Decision table (pre-committed):
//   FETCH >= 2GiB            -> RFO on real stores; attack allocation policy.
//   FETCH ~0, dur-R4 ~ 512us -> store cap independent of source; clone fill's
//                               launch shape (tiny grid, ~1 block/CU).
//   FETCH ~0, dur-R4 ~ 390us -> loaded-data dependency; enforced-distance
//                               register prefetch.
//   aggregate hbm ~6.2       -> stream is fine; deficit is outside this kernel.

#define NBINS 15
#define NPTS  1536
#define DPAIR 128
#define NPAIR (NPTS * NPTS)                  // 2359296 pairs
#define TOT_F4 (NPAIR * (DPAIR / 4))         // 75497472 output float4
#define SBLOCKS 2048
#define NT (SBLOCKS * 256)                   // 524288 threads
#define NITER (TOT_F4 / NT)                  // 144, exact (no tail)

#define TAB_BYTES (16 * DPAIR * 4)           // 8192
#define WS_NEEDED (TAB_BYTES + NPAIR)        // 8 KB + 2.36 MB

typedef float f32x4 __attribute__((ext_vector_type(4)));

// ---------------- dispatch 1: prep (idx table + expanded row table) ---------
__global__ __launch_bounds__(256) void prep_kernel(
    const float* __restrict__ x,   // [NPTS,3]
    const float* __restrict__ W,   // [DPAIR,NBINS] row-major
    const float* __restrict__ b,   // [DPAIR]
    float* __restrict__ tab,       // [16*DPAIR] in ws
    unsigned char* __restrict__ idx) {  // [NPAIR] in ws
    const int i = blockIdx.x;
    const int t = threadIdx.x;

    // squared bin edges: exact multiples of 0.25 -> exact fp32; squaring
    // rounds identically to numpy's **2 in float32.
    float bins[NBINS];
#pragma unroll
    for (int k = 0; k < NBINS; ++k) {
        float e = 3.25f + 1.25f * (float)k;
        bins[k] = e * e;
    }

    // Block 0 additionally builds the 16-row table (row 0 = b, row k = b+W[:,k-1]).
    if (i == 0) {
        for (int e = t; e < 16 * DPAIR; e += 256) {
            int row = e >> 7;            // 0..15
            int p   = e & (DPAIR - 1);
            float v = b[p];
            if (row > 0) v += W[p * NBINS + (row - 1)];
            tab[e] = v;
        }
    }

    const float xi0 = x[i * 3 + 0];
    const float xi1 = x[i * 3 + 1];
    const float xi2 = x[i * 3 + 2];
    for (int j = t; j < NPTS; j += 256) {
        float d;
        {
            // Bit-exact vs numpy: individually-rounded squares, left-to-right
            // sum, no fma contraction.
#pragma clang fp contract(off)
            float dx = xi0 - x[j * 3 + 0];
            float dy = xi1 - x[j * 3 + 1];
            float dz = xi2 - x[j * 3 + 2];
            d = dx * dx + dy * dy + dz * dz;
        }
        int cnt = 0, eq = 0;
#pragma unroll
        for (int k = 0; k < NBINS; ++k) {
            cnt += (d > bins[k]) ? 1 : 0;
            eq  |= (d == bins[k]) ? 1 : 0;
        }
        // exact edge hit -> one-hot all zero -> row 0 (b only)
        idx[i * NPTS + j] = (unsigned char)(eq ? 0 : cnt);
    }
}

// ------ dispatch 2 (DIAGNOSTIC): 2x const sweep + 2x real sweep -------------
__global__ __launch_bounds__(256, 8) void stream_kernel(
    const float* __restrict__ tab,           // [16*DPAIR] in ws
    const unsigned char* __restrict__ idx,   // [NPAIR] in ws
    float* __restrict__ out) {               // [NPTS,NPTS,DPAIR]
    const f32x4* tab4 = (const f32x4*)tab;
    f32x4* out4 = (f32x4*)out;

    const unsigned flat = blockIdx.x * 256u + threadIdx.x;
    const unsigned w = flat & 31u;           // thread-constant f4 lane in feature row

    // --- 2x CONST sweep: identical addresses, register-constant data -------
    const f32x4 cval = {0.f, 0.f, 0.f, 0.f};
#pragma unroll 1
    for (int rep = 0; rep < 2; ++rep) {
#pragma unroll 4
        for (int it = 0; it < NITER; ++it) {
            unsigned g = flat + (unsigned)it * (unsigned)NT;
            out4[g] = cval;
        }
        // Memory clobber: stores above may be observed -> no dead-store elim.
        asm volatile("" ::: "memory");
    }

    // --- 2x REAL sweep: the actual table lookup (last pass = final output) --
#pragma unroll 1
    for (int rep = 0; rep < 2; ++rep) {
#pragma unroll 4
        for (int it = 0; it < NITER; ++it) {
            unsigned g = flat + (unsigned)it * (unsigned)NT;  // global f4 index
            unsigned p = g >> 5;                 // pair index (i*NPTS+j)
            unsigned id = idx[p];                // broadcast byte, L1/L2-resident
            out4[g] = tab4[id * 32u + w];        // 16B from L1-resident 8KB table
        }
        asm volatile("" ::: "memory");
    }
}

// ---------------- fallback (R1 kernel) if ws is too small -------------------
#define JSPLIT 2
#define JCHUNK (NPTS / JSPLIT)
#define CHUNK_F4 (JCHUNK * DPAIR / 4)

__global__ __launch_bounds__(256, 8) void recycling_embedder_fallback(
    const float* __restrict__ x,
    const float* __restrict__ W,
    const float* __restrict__ b,
    float* __restrict__ out) {
    __shared__ float table[16 * DPAIR];
    __shared__ unsigned short offs[JCHUNK];

    const int i    = blockIdx.x >> 1;
    const int half = blockIdx.x & 1;
    const int t    = threadIdx.x;

    float bins[NBINS];
#pragma unroll
    for (int k = 0; k < NBINS; ++k) {
        float e = 3.25f + 1.25f * (float)k;
        bins[k] = e * e;
    }

    for (int e = t; e < 16 * DPAIR; e += 256) {
        int row = e >> 7;
        int p   = e & (DPAIR - 1);
        float v = b[p];
        if (row > 0) v += W[p * NBINS + (row - 1)];
        table[e] = v;
    }

    const float xi0 = x[i * 3 + 0];
    const float xi1 = x[i * 3 + 1];
    const float xi2 = x[i * 3 + 2];
    const int j0 = half * JCHUNK;
    for (int jj = t; jj < JCHUNK; jj += 256) {
        int j = j0 + jj;
        float d;
        {
#pragma clang fp contract(off)
            float dx = xi0 - x[j * 3 + 0];
            float dy = xi1 - x[j * 3 + 1];
            float dz = xi2 - x[j * 3 + 2];
            d = dx * dx + dy * dy + dz * dz;
        }
        int cnt = 0, eq = 0;
#pragma unroll
        for (int k = 0; k < NBINS; ++k) {
            cnt += (d > bins[k]) ? 1 : 0;
            eq  |= (d == bins[k]) ? 1 : 0;
        }
        int bidx = eq ? 0 : cnt;
        offs[jj] = (unsigned short)(bidx * (DPAIR / 4));
    }
    __syncthreads();

    const f32x4* table4 = (const f32x4*)table;
    f32x4* ochunk = (f32x4*)out
                  + (size_t)i * (NPTS * DPAIR / 4)
                  + (size_t)(j0 * (DPAIR / 4));
#pragma unroll 4
    for (int l = t; l < CHUNK_F4; l += 256) {
        int jj     = l >> 5;
        int within = l & 31;
        ochunk[l] = table4[offs[jj] + within];
    }
}

extern "C" void kernel_launch(void* const* d_in, const int* in_sizes, int n_in,
                              void* d_out, int out_size, void* d_ws, size_t ws_size,
                              hipStream_t stream) {
    const float* x = (const float*)d_in[0];
    const float* W = (const float*)d_in[1];
    const float* b = (const float*)d_in[2];
    float* out = (float*)d_out;

    if (ws_size >= (size_t)WS_NEEDED && d_ws != nullptr) {
        float* tab = (float*)d_ws;
        unsigned char* idx = (unsigned char*)d_ws + TAB_BYTES;

        // Dispatch 1: per-pair bin index + expanded table (~15 us).
        prep_kernel<<<dim3(NPTS), dim3(256), 0, stream>>>(x, W, b, tab, idx);
        // Dispatch 2: DIAGNOSTIC 4-sweep writer (2x const, 2x real) so the
        // dispatch outlasts the ~770us poison fills and surfaces in top-5.
        stream_kernel<<<dim3(SBLOCKS), dim3(256), 0, stream>>>(tab, idx, out);
    } else {
        recycling_embedder_fallback<<<dim3(NPTS * JSPLIT), dim3(256), 0, stream>>>(
            x, W, b, out);
    }
}

// Round 8
// 1472.891 us; speedup vs baseline: 1.2252x; 1.2252x over previous
//
#include <hip/hip_runtime.h>

// RecyclingEmbedder: out[i][j][p] = b[p] + (bin(d_ij) fired ? W[p][bin] : 0)
// Output = 16-row table lookup -> pure write-BW problem (1.208 GB fp32).
//
// History:
//  R2(s1): nontemporal ~1.0 TB/s -> plain stores. R1: 32 waves: null.
//  R3: fill-clone flat sweep: null. R5: LDS SW-pipeline: null.
//  R7 DIAG (counters!): FETCH~0 (no RFO). OH(harness fill+memsets+gaps) = 919.5us.
//    const-store sweep in our context = ~172us (7.0 TB/s!); real table-lookup
//    sweep = ~255-286us (4.2-4.7 TB/s) across ALL structures.
//    => the ~90us/sweep penalty appears ONLY when store data depends on a load.
//
// R8: ZERO-LOAD hot loop. Table held in 16 per-thread f32x4 REGISTERS (each
// thread only needs its own w-slice); store value picked by a 4-level
// v_cndmask tree (15 f32x4 selects); ids delivered 8-at-a-time from a tiny
// transposed LDS array via double-buffered ds_read_b64. The streaming loop
// issues NOTHING but stores to the memory system.
// Prediction: stream 254 -> 175-200us => dur ~1080-1110. Null (~1160) =>
// store-BW is data-content-dependent (const sweep wrote zeros; compression)
// => we are at the real-data roofline and declare next round.

#define NBINS 15
#define NPTS  1536
#define DPAIR 128
#define JSPLIT 2
#define JCHUNK (NPTS / JSPLIT)          // 768 pairs per block
#define NPACK  12                       // 12 packs x 8 iters x 256 thr = 24576 f4

typedef float f32x4 __attribute__((ext_vector_type(4)));

// per-component ternary -> v_cmp (CSE'd) + 4 v_cndmask
static __device__ __forceinline__ f32x4 sel(int c, f32x4 a, f32x4 b) {
    f32x4 r;
    r[0] = c ? a[0] : b[0];
    r[1] = c ? a[1] : b[1];
    r[2] = c ? a[2] : b[2];
    r[3] = c ? a[3] : b[3];
    return r;
}

__global__ __launch_bounds__(256, 4) void recycling_embedder_kernel(
    const float* __restrict__ x,   // [NPTS,3]
    const float* __restrict__ W,   // [DPAIR,NBINS] row-major
    const float* __restrict__ b,   // [DPAIR]
    float* __restrict__ out) {     // [NPTS,NPTS,DPAIR]
    __shared__ __align__(16) float table[16 * DPAIR];      // 8 KB
    // ids transposed: idsT[col*96 + g] = id of pair jj = col + 8*g.
    // Thread t needs col = t>>5, g = 0..95 -> 12x aligned ds_read_b64.
    __shared__ __align__(8) unsigned char idsT[8 * 96];    // 768 B

    const int i    = blockIdx.x >> 1;   // output row
    const int half = blockIdx.x & 1;    // which j-half of the row
    const int t    = threadIdx.x;

    // squared bin edges: exact multiples of 0.25 -> exact fp32; squaring
    // rounds identically to numpy's **2 in float32.
    float bins[NBINS];
#pragma unroll
    for (int k = 0; k < NBINS; ++k) {
        float e = 3.25f + 1.25f * (float)k;
        bins[k] = e * e;
    }

    // Build the 16-row lookup table (row 0 = b only; row k = b + W[:,k-1]).
    for (int e = t; e < 16 * DPAIR; e += 256) {
        int row = e >> 7;            // 0..15
        int p   = e & (DPAIR - 1);
        float v = b[p];
        if (row > 0) v += W[p * NBINS + (row - 1)];
        table[e] = v;
    }

    // Per-j bin index, stored transposed for the 8-wide id packs.
    const float xi0 = x[i * 3 + 0];
    const float xi1 = x[i * 3 + 1];
    const float xi2 = x[i * 3 + 2];
    const int j0 = half * JCHUNK;
    for (int jj = t; jj < JCHUNK; jj += 256) {
        int j = j0 + jj;
        float d;
        {
            // Bit-exact vs numpy: individually-rounded squares, left-to-right
            // sum, no fma contraction.
#pragma clang fp contract(off)
            float dx = xi0 - x[j * 3 + 0];
            float dy = xi1 - x[j * 3 + 1];
            float dz = xi2 - x[j * 3 + 2];
            d = dx * dx + dy * dy + dz * dz;
        }
        int cnt = 0, eq = 0;
#pragma unroll
        for (int k = 0; k < NBINS; ++k) {
            cnt += (d > bins[k]) ? 1 : 0;
            eq  |= (d == bins[k]) ? 1 : 0;
        }
        // exact edge hit -> one-hot all zero -> row 0 (b only)
        idsT[(jj & 7) * 96 + (jj >> 3)] = (unsigned char)(eq ? 0 : cnt);
    }
    __syncthreads();

    // ---- hoist this thread's w-slice of all 16 table rows into registers ----
    const char* tabc = (const char*)table;
    const int wb = (t & 31) * 16;   // byte offset of this thread's f32x4 slice
    f32x4 t0  = *(const f32x4*)(tabc +  0 * 512 + wb);
    f32x4 t1  = *(const f32x4*)(tabc +  1 * 512 + wb);
    f32x4 t2  = *(const f32x4*)(tabc +  2 * 512 + wb);
    f32x4 t3  = *(const f32x4*)(tabc +  3 * 512 + wb);
    f32x4 t4  = *(const f32x4*)(tabc +  4 * 512 + wb);
    f32x4 t5  = *(const f32x4*)(tabc +  5 * 512 + wb);
    f32x4 t6  = *(const f32x4*)(tabc +  6 * 512 + wb);
    f32x4 t7  = *(const f32x4*)(tabc +  7 * 512 + wb);
    f32x4 t8  = *(const f32x4*)(tabc +  8 * 512 + wb);
    f32x4 t9  = *(const f32x4*)(tabc +  9 * 512 + wb);
    f32x4 t10 = *(const f32x4*)(tabc + 10 * 512 + wb);
    f32x4 t11 = *(const f32x4*)(tabc + 11 * 512 + wb);
    f32x4 t12 = *(const f32x4*)(tabc + 12 * 512 + wb);
    f32x4 t13 = *(const f32x4*)(tabc + 13 * 512 + wb);
    f32x4 t14 = *(const f32x4*)(tabc + 14 * 512 + wb);
    f32x4 t15 = *(const f32x4*)(tabc + 15 * 512 + wb);

    const unsigned char* idcol = &idsT[(t >> 5) * 96];   // this thread's column
    f32x4* pout = (f32x4*)out
                + (size_t)i * (NPTS * DPAIR / 4)
                + (size_t)(j0 * (DPAIR / 4))
                + t;

    // 4-level cndmask tree: 15 f32x4 selects, zero memory traffic.
#define SELECT(idv, dst) do {                                              \
        int b0_ = (idv) & 1, b1_ = (idv) & 2, b2_ = (idv) & 4,             \
            b3_ = (idv) & 8;                                               \
        f32x4 a0_ = sel(b0_, t1,  t0),  a1_ = sel(b0_, t3,  t2);           \
        f32x4 a2_ = sel(b0_, t5,  t4),  a3_ = sel(b0_, t7,  t6);           \
        f32x4 a4_ = sel(b0_, t9,  t8),  a5_ = sel(b0_, t11, t10);          \
        f32x4 a6_ = sel(b0_, t13, t12), a7_ = sel(b0_, t15, t14);          \
        f32x4 c0_ = sel(b1_, a1_, a0_), c1_ = sel(b1_, a3_, a2_);          \
        f32x4 c2_ = sel(b1_, a5_, a4_), c3_ = sel(b1_, a7_, a6_);          \
        f32x4 d0_ = sel(b2_, c1_, c0_), d1_ = sel(b2_, c3_, c2_);          \
        dst = sel(b3_, d1_, d0_);                                          \
    } while (0)

#define ITER(word, sh, u) do {                                             \
        int id_ = ((word) >> (sh)) & 15;                                   \
        f32x4 v_;                                                          \
        SELECT(id_, v_);                                                   \
        pout[(u) * 256] = v_;                                              \
    } while (0)

#define PROC(PK) do {                                                      \
        unsigned lo_ = (PK).x, hi_ = (PK).y;                               \
        ITER(lo_,  0, 0); ITER(lo_,  8, 1);                                \
        ITER(lo_, 16, 2); ITER(lo_, 24, 3);                                \
        ITER(hi_,  0, 4); ITER(hi_,  8, 5);                                \
        ITER(hi_, 16, 6); ITER(hi_, 24, 7);                                \
        pout += 8 * 256;                                                   \
    } while (0)

    // Double-buffered id packs: one 8-byte LDS read per 8 stores.
    uint2 pA = *(const uint2*)(idcol + 0 * 8);
#pragma unroll 1
    for (int k = 0; k < NPACK - 2; k += 2) {
        uint2 pB = *(const uint2*)(idcol + (k + 1) * 8);
        PROC(pA);                               // pack k
        pA = *(const uint2*)(idcol + (k + 2) * 8);
        PROC(pB);                               // pack k+1
    }
    {   // epilogue: packs NPACK-2 (in pA) and NPACK-1
        uint2 pB = *(const uint2*)(idcol + (NPACK - 1) * 8);
        PROC(pA);
        PROC(pB);
    }

#undef SELECT
#undef ITER
#undef PROC
}

extern "C" void kernel_launch(void* const* d_in, const int* in_sizes, int n_in,
                              void* d_out, int out_size, void* d_ws, size_t ws_size,
                              hipStream_t stream) {
    const float* x = (const float*)d_in[0];
    const float* W = (const float*)d_in[1];
    const float* b = (const float*)d_in[2];
    float* out = (float*)d_out;

    // 2 blocks per output row i: 3072 blocks, lb(256,4) -> ~16 waves/CU.
    // (Fill hits 6.27 TB/s at ~3 waves/CU; write BW needs no occupancy.)
    dim3 grid(NPTS * JSPLIT), block(256);
    recycling_embedder_kernel<<<grid, block, 0, stream>>>(x, W, b, out);
}

// Round 9
// 1187.414 us; speedup vs baseline: 1.5197x; 1.2404x over previous
//
#include <hip/hip_runtime.h>

// RecyclingEmbedder: out[i][j][p] = b[p] + (bin(d_ij) fired ? W[p][bin] : 0)
// Output = 16-row table lookup -> pure write-BW problem (1.208 GB fp32).
//
// History:
//  R7 DIAG (direct counters): FETCH~0 (no RFO). Harness overhead ~905-920us
//    (poison fill ~770 + memsets/gaps). Const(zero)-store sweep in our context
//    ~172us (7.0 TB/s); every real-data sweep ~254-286us (4.7 TB/s) across 5
//    structures, incl. R4's identical-rewrite pass.
//  R8: register-table + 8 interleaved tree-selects under lb(256,4) ->
//    ~110+ live f32x4 temps -> VGPR SPILL -> stream ~555us. Theory UNTESTED.
//
// R9 = spill-free rerun of the load-free design (discriminator + candidate win):
//  - sequential single-accumulator cndmask select (15 x [v_cmp_eq + 4 cndmask]),
//    peak live ~110 VGPR even with 8-way store interleave.
//  - lb(256,2): 256-VGPR cap -> spill impossible; 8 waves/CU is ample for
//    store BW (harness fill does 6.27 TB/s at 10% occupancy).
//  - unroll 1 over 12 id-packs: hot body ~5KB, I-cache safe.
//  - store data path: registers -> VALU select -> store. The only load in the
//    loop (uint2 id pack from LDS) is consumed 8+ stores ahead (pA/pB,
//    static names).
// Decision: dur ~1075-1105 => load-dependency was the cap (keep).
//           dur ~1155-1180 => content-dependent write BW => ROOFLINE next round.

#define NBINS 15
#define NPTS  1536
#define DPAIR 128
#define JSPLIT 2
#define JCHUNK (NPTS / JSPLIT)          // 768 pairs per block
#define NPACK  12                       // 12 packs x 8 iters x 256 thr = 24576 f4

typedef float f32x4 __attribute__((ext_vector_type(4)));

// per-component ternary -> one v_cmp (CSE'd across components) + 4 v_cndmask
static __device__ __forceinline__ f32x4 sel(int c, f32x4 a, f32x4 b) {
    f32x4 r;
    r[0] = c ? a[0] : b[0];
    r[1] = c ? a[1] : b[1];
    r[2] = c ? a[2] : b[2];
    r[3] = c ? a[3] : b[3];
    return r;
}

__global__ __launch_bounds__(256, 2) void recycling_embedder_kernel(
    const float* __restrict__ x,   // [NPTS,3]
    const float* __restrict__ W,   // [DPAIR,NBINS] row-major
    const float* __restrict__ b,   // [DPAIR]
    float* __restrict__ out) {     // [NPTS,NPTS,DPAIR]
    __shared__ __align__(16) float table[16 * DPAIR];      // 8 KB
    // ids transposed: idsT[col*96 + g] = id of pair jj = col + 8*g.
    // Thread t needs col = t>>5, g = 0..95 -> 12x aligned 8B reads (broadcast
    // within each 32-thread group -> conflict-free).
    __shared__ __align__(8) unsigned char idsT[8 * 96];    // 768 B

    const int i    = blockIdx.x >> 1;   // output row
    const int half = blockIdx.x & 1;    // which j-half of the row
    const int t    = threadIdx.x;

    // squared bin edges: exact multiples of 0.25 -> exact fp32; squaring
    // rounds identically to numpy's **2 in float32.
    float bins[NBINS];
#pragma unroll
    for (int k = 0; k < NBINS; ++k) {
        float e = 3.25f + 1.25f * (float)k;
        bins[k] = e * e;
    }

    // Build the 16-row lookup table (row 0 = b only; row k = b + W[:,k-1]).
    for (int e = t; e < 16 * DPAIR; e += 256) {
        int row = e >> 7;            // 0..15
        int p   = e & (DPAIR - 1);
        float v = b[p];
        if (row > 0) v += W[p * NBINS + (row - 1)];
        table[e] = v;
    }

    // Per-j bin index, stored transposed for the 8-wide id packs.
    const float xi0 = x[i * 3 + 0];
    const float xi1 = x[i * 3 + 1];
    const float xi2 = x[i * 3 + 2];
    const int j0 = half * JCHUNK;
    for (int jj = t; jj < JCHUNK; jj += 256) {
        int j = j0 + jj;
        float d;
        {
            // Bit-exact vs numpy: individually-rounded squares, left-to-right
            // sum, no fma contraction.
#pragma clang fp contract(off)
            float dx = xi0 - x[j * 3 + 0];
            float dy = xi1 - x[j * 3 + 1];
            float dz = xi2 - x[j * 3 + 2];
            d = dx * dx + dy * dy + dz * dz;
        }
        int cnt = 0, eq = 0;
#pragma unroll
        for (int k = 0; k < NBINS; ++k) {
            cnt += (d > bins[k]) ? 1 : 0;
            eq  |= (d == bins[k]) ? 1 : 0;
        }
        // exact edge hit -> one-hot all zero -> row 0 (b only)
        idsT[(jj & 7) * 96 + (jj >> 3)] = (unsigned char)(eq ? 0 : cnt);
    }
    __syncthreads();

    // ---- hoist this thread's w-slice of all 16 table rows into registers ----
    const char* tabc = (const char*)table;
    const int wb = (t & 31) * 16;   // byte offset of this thread's f32x4 slice
    f32x4 t0  = *(const f32x4*)(tabc +  0 * 512 + wb);
    f32x4 t1  = *(const f32x4*)(tabc +  1 * 512 + wb);
    f32x4 t2  = *(const f32x4*)(tabc +  2 * 512 + wb);
    f32x4 t3  = *(const f32x4*)(tabc +  3 * 512 + wb);
    f32x4 t4  = *(const f32x4*)(tabc +  4 * 512 + wb);
    f32x4 t5  = *(const f32x4*)(tabc +  5 * 512 + wb);
    f32x4 t6  = *(const f32x4*)(tabc +  6 * 512 + wb);
    f32x4 t7  = *(const f32x4*)(tabc +  7 * 512 + wb);
    f32x4 t8  = *(const f32x4*)(tabc +  8 * 512 + wb);
    f32x4 t9  = *(const f32x4*)(tabc +  9 * 512 + wb);
    f32x4 t10 = *(const f32x4*)(tabc + 10 * 512 + wb);
    f32x4 t11 = *(const f32x4*)(tabc + 11 * 512 + wb);
    f32x4 t12 = *(const f32x4*)(tabc + 12 * 512 + wb);
    f32x4 t13 = *(const f32x4*)(tabc + 13 * 512 + wb);
    f32x4 t14 = *(const f32x4*)(tabc + 14 * 512 + wb);
    f32x4 t15 = *(const f32x4*)(tabc + 15 * 512 + wb);

    const unsigned char* idcol = &idsT[(t >> 5) * 96];   // this thread's column
    f32x4* pout = (f32x4*)out
                + (size_t)i * (NPTS * DPAIR / 4)
                + (size_t)(j0 * (DPAIR / 4))
                + t;

    // Sequential 1-of-16 select: single accumulator, 15 x (cmp + 4 cndmask).
    // Low register pressure even when the compiler interleaves 8 stores.
#define SELECT(idv, dst) do {                                              \
        f32x4 v_ = t0;                                                     \
        v_ = sel((idv) ==  1, t1,  v_);                                    \
        v_ = sel((idv) ==  2, t2,  v_);                                    \
        v_ = sel((idv) ==  3, t3,  v_);                                    \
        v_ = sel((idv) ==  4, t4,  v_);                                    \
        v_ = sel((idv) ==  5, t5,  v_);                                    \
        v_ = sel((idv) ==  6, t6,  v_);                                    \
        v_ = sel((idv) ==  7, t7,  v_);                                    \
        v_ = sel((idv) ==  8, t8,  v_);                                    \
        v_ = sel((idv) ==  9, t9,  v_);                                    \
        v_ = sel((idv) == 10, t10, v_);                                    \
        v_ = sel((idv) == 11, t11, v_);                                    \
        v_ = sel((idv) == 12, t12, v_);                                    \
        v_ = sel((idv) == 13, t13, v_);                                    \
        v_ = sel((idv) == 14, t14, v_);                                    \
        v_ = sel((idv) == 15, t15, v_);                                    \
        dst = v_;                                                          \
    } while (0)

#define ITER(word, sh, u) do {                                             \
        int id_ = (int)(((word) >> (sh)) & 15u);                           \
        f32x4 o_;                                                          \
        SELECT(id_, o_);                                                   \
        pout[(u) * 256] = o_;                                              \
    } while (0)

#define PROC(PK) do {                                                      \
        unsigned lo_ = (PK).x, hi_ = (PK).y;                               \
        ITER(lo_,  0, 0); ITER(lo_,  8, 1);                                \
        ITER(lo_, 16, 2); ITER(lo_, 24, 3);                                \
        ITER(hi_,  0, 4); ITER(hi_,  8, 5);                                \
        ITER(hi_, 16, 6); ITER(hi_, 24, 7);                                \
        pout += 8 * 256;                                                   \
    } while (0)

    // Double-buffered id packs: one 8-byte LDS read per 8 stores, consumed a
    // full pack (8 stores) after it is issued -> never on the store's
    // data-dependence critical path.
    uint2 pA = *(const uint2*)(idcol + 0 * 8);
#pragma unroll 1
    for (int k = 0; k < NPACK - 2; k += 2) {
        uint2 pB = *(const uint2*)(idcol + (k + 1) * 8);
        PROC(pA);                               // pack k
        pA = *(const uint2*)(idcol + (k + 2) * 8);
        PROC(pB);                               // pack k+1
    }
    {   // epilogue: packs NPACK-2 (in pA) and NPACK-1
        uint2 pB = *(const uint2*)(idcol + (NPACK - 1) * 8);
        PROC(pA);
        PROC(pB);
    }

#undef SELECT
#undef ITER
#undef PROC
}

extern "C" void kernel_launch(void* const* d_in, const int* in_sizes, int n_in,
                              void* d_out, int out_size, void* d_ws, size_t ws_size,
                              hipStream_t stream) {
    const float* x = (const float*)d_in[0];
    const float* W = (const float*)d_in[1];
    const float* b = (const float*)d_in[2];
    float* out = (float*)d_out;

    // 2 blocks per output row i: 3072 blocks, lb(256,2) -> no spill possible;
    // 8 waves/CU (fill hits 6.27 TB/s at ~3 waves/CU, so this is ample).
    dim3 grid(NPTS * JSPLIT), block(256);
    recycling_embedder_kernel<<<grid, block, 0, stream>>>(x, W, b, out);
}